// Round 8
// baseline (915.574 us; speedup 1.0000x reference)
//
#include <hip/hip_runtime.h>

#define BATCH  4096
#define TSTEPS 64
#define FDIM   128
#define HDIM   256
#define ODIM   64
#define MROWS  32
#define NBLK   128    // BATCH / MROWS
#define NTHR   1024   // 16 waves; 4 waves/SIMD

typedef __attribute__((ext_vector_type(8))) short  short8;
typedef __attribute__((ext_vector_type(4))) float  floatx4;

#define MFMA(a,b,c) __builtin_amdgcn_mfma_f32_16x16x32_bf16((a),(b),(c),0,0,0)

__device__ __forceinline__ unsigned short f2bf(float f){
  unsigned u = __builtin_bit_cast(unsigned, f);
  u += 0x7FFFu + ((u >> 16) & 1u);           // RTNE
  return (unsigned short)(u >> 16);
}
__device__ __forceinline__ float sigm(float x){
  return __builtin_amdgcn_rcpf(1.f + __expf(-x));
}
__device__ __forceinline__ float tanh_f(float x){
  return 2.f * __builtin_amdgcn_rcpf(1.f + __expf(-2.f * x)) - 1.f;
}

// ---------------- phase 0: fragment weights into d_ws ----------
// warr[((gf*12 + kf)*64 + lane)*8 + i]; gf 0..47, kf 0..7 = w_hh, 8..11 = w_ih
// element = W[16*gf + (lane&15)][32*kf + 8*(lane>>4) + i]  (A-frag, row=lane&15)
__global__ void prep_weights(const float* __restrict__ w_ih,
                             const float* __restrict__ w_hh,
                             unsigned short* __restrict__ warr){
  int idx = blockIdx.x * 256 + threadIdx.x;
  if (idx >= 48*12*64) return;
  int gf   = idx / 768;
  int rr   = idx - gf*768;
  int kf   = rr >> 6;
  int lane = rr & 63;
  int lo = lane & 15, hi = lane >> 4;
  const float* src = (kf < 8) ? (w_hh + (size_t)(16*gf + lo)*HDIM + 32*kf     + 8*hi)
                              : (w_ih + (size_t)(16*gf + lo)*FDIM + 32*(kf-8) + 8*hi);
  unsigned short* dst = warr + (size_t)idx * 8;
  #pragma unroll
  for (int i = 0; i < 8; ++i) dst[i] = f2bf(src[i]);
}

// ---- LDS swizzle (bank-quad = (col>>4) ^ (row&7) -> natural 8-lane groups
// span all 8 quads; conflict-free for b128 reads and 8B packed writes)
__device__ __forceinline__ short8 ldsH(const unsigned char* sm, int row, int col){
  return *(const short8*)(sm + row*512 + (col ^ ((row & 7) << 4)));
}
__device__ __forceinline__ short8 ldsX(const unsigned char* sm, int row, int col){
  return *(const short8*)(sm + row*256 + (col ^ ((row & 7) << 4)));
}

// ---------------- main fused kernel ----------------
template<int KOFF>
__device__ __forceinline__ void gru_body(
    const float* __restrict__ feat, const unsigned short* __restrict__ warr,
    const float* __restrict__ b_ih, const float* __restrict__ b_hh,
    const float* __restrict__ w_pi, const float* __restrict__ b_pi,
    const float* __restrict__ w_vf, const float* __restrict__ b_vf,
    float* __restrict__ out,
    unsigned char* sm_h, unsigned char* sm_x, float* biasL){

  const int tid  = threadIdx.x;
  const int wv   = tid >> 6;              // 0..15 -> owns h-cols [16wv, 16wv+16)
  const int lane = tid & 63;
  const int lo   = lane & 15, hi = lane >> 4;
  const int row0 = blockIdx.x * MROWS;
  const int cb   = 16*wv + 4*hi;          // gate/h col base for this lane
  const int gfr  = wv, gfz = 16 + wv, gfn = 32 + wv;

  const unsigned short* wl = warr + lane*8;

  // ---- one-time: bias -> LDS
  if      (tid < 512) biasL[tid] = b_ih[tid] + b_hh[tid];   // r,z combined
  else if (tid < 768) biasL[tid] = b_ih[tid];               // xn
  else                biasL[tid] = b_hh[tid - 256];         // hn

  // ---- zero sm_h
  ((int4*)sm_h)[tid] = make_int4(0,0,0,0);
  // ---- stage x[0]
  {
    int r  = tid >> 5;
    int c4 = tid & 31;
    floatx4 v = __builtin_nontemporal_load(
        (const floatx4*)(feat + (size_t)(row0 + r)*(TSTEPS*FDIM)) + c4);
    uint2 pk;
    pk.x = (unsigned)f2bf(v[0]) | ((unsigned)f2bf(v[1]) << 16);
    pk.y = (unsigned)f2bf(v[2]) | ((unsigned)f2bf(v[3]) << 16);
    *(uint2*)(sm_x + r*256 + ((c4*8) ^ ((r & 7) << 4))) = pk;
  }

  float hold[2][4];
  #pragma unroll
  for (int m = 0; m < 2; ++m)
    #pragma unroll
    for (int j = 0; j < 4; ++j) hold[m][j] = 0.f;

  __syncthreads();

  const int xr  = tid >> 5;
  const int xc4 = tid & 31;

  #pragma unroll 1
  for (int t = 0; t < TSTEPS; ++t){
    // ---- prefetch x[t+1]
    int tn = (t < TSTEPS-1) ? (t+1) : (TSTEPS-1);
    floatx4 xf = __builtin_nontemporal_load(
        (const floatx4*)(feat + (size_t)(row0 + xr)*(TSTEPS*FDIM) + (size_t)tn*FDIM) + xc4);

    // ---- acc init from LDS bias
    floatx4 ar[2], az[2], anh[2], anx[2];
    {
      floatx4 vr = *(const floatx4*)(biasL + cb);
      floatx4 vz = *(const floatx4*)(biasL + 256 + cb);
      floatx4 vx = *(const floatx4*)(biasL + 512 + cb);
      floatx4 vh = *(const floatx4*)(biasL + 768 + cb);
      #pragma unroll
      for (int m = 0; m < 2; ++m){ ar[m] = vr; az[m] = vz; anh[m] = vh; anx[m] = vx; }
    }

    // ---- software-pipelined K loop: 12 rounds, A prefetched 1 round ahead
    constexpr int K0 = KOFF % 12;
    short8 a0c = *(const short8*)(wl + (gfr*12 + K0)*512);
    short8 a1c = *(const short8*)(wl + (gfz*12 + K0)*512);
    short8 a2c = *(const short8*)(wl + (gfn*12 + K0)*512);
    #pragma unroll
    for (int g = 0; g < 12; ++g){
      const int kf = (g + KOFF) % 12;
      short8 a0n, a1n, a2n;
      if (g < 11){
        const int k2 = (g + 1 + KOFF) % 12;
        a0n = *(const short8*)(wl + (gfr*12 + k2)*512);
        a1n = *(const short8*)(wl + (gfz*12 + k2)*512);
        a2n = *(const short8*)(wl + (gfn*12 + k2)*512);
      }
      #pragma unroll
      for (int m = 0; m < 2; ++m){
        short8 b = (kf < 8) ? ldsH(sm_h, 16*m + lo, kf*64 + hi*16)
                            : ldsX(sm_x, 16*m + lo, (kf-8)*64 + hi*16);
        ar[m] = MFMA(a0c, b, ar[m]);
        az[m] = MFMA(a1c, b, az[m]);
        if (kf < 8) anh[m] = MFMA(a2c, b, anh[m]);
        else        anx[m] = MFMA(a2c, b, anx[m]);
      }
      a0c = a0n; a1c = a1n; a2c = a2n;
    }
    __syncthreads();   // all sm_h / sm_x reads of this step done

    // ---- write x[t+1]
    if (t < TSTEPS-1){
      uint2 pk;
      pk.x = (unsigned)f2bf(xf[0]) | ((unsigned)f2bf(xf[1]) << 16);
      pk.y = (unsigned)f2bf(xf[2]) | ((unsigned)f2bf(xf[3]) << 16);
      *(uint2*)(sm_x + xr*256 + ((xc4*8) ^ ((xr & 7) << 4))) = pk;
    }

    // ---- lane-local gate math; write h_new (bf16, swizzled, 8B packed)
    #pragma unroll
    for (int m = 0; m < 2; ++m){
      int row = 16*m + lo;
      unsigned q[4];
      #pragma unroll
      for (int j = 0; j < 4; ++j){
        float r  = sigm(ar[m][j]);
        float z  = sigm(az[m][j]);
        float n  = tanh_f(anx[m][j] + r*anh[m][j]);
        float hv = (1.f - z)*n + z*hold[m][j];
        hold[m][j] = hv;
        q[j] = f2bf(hv);
      }
      uint2 pk; pk.x = q[0] | (q[1] << 16); pk.y = q[2] | (q[3] << 16);
      *(uint2*)(sm_h + row*512 + ((cb*2) ^ ((row & 7) << 4))) = pk;
    }
    __syncthreads();   // h[t+1], x[t+1] visible
  }

  // ---- epilogue: leaky(h_last) -> sm_h (bf16)
  #pragma unroll
  for (int m = 0; m < 2; ++m){
    int row = 16*m + lo;
    unsigned q[4];
    #pragma unroll
    for (int j = 0; j < 4; ++j){
      float v = hold[m][j];
      v = (v >= 0.f) ? v : 0.01f*v;
      q[j] = f2bf(v);
    }
    uint2 pk; pk.x = q[0] | (q[1] << 16); pk.y = q[2] | (q[3] << 16);
    *(uint2*)(sm_h + row*512 + ((cb*2) ^ ((row & 7) << 4))) = pk;
  }
  __syncthreads();

  // ---- heads: 16 waves = 2 heads x 4 out-frags x 2 row-frags
  const int head = wv >> 3;
  const int mfo  = (wv >> 1) & 3;
  const int rh   = wv & 1;
  const float* wh = head ? w_vf : w_pi;
  const float* bh = head ? b_vf : b_pi;
  floatx4 acc = {0.f,0.f,0.f,0.f};
  #pragma unroll
  for (int kf = 0; kf < 8; ++kf){
    const float* ap = wh + (size_t)(16*mfo + lo)*HDIM + 32*kf + 8*hi;
    floatx4 av0 = *(const floatx4*)ap;
    floatx4 av1 = *(const floatx4*)(ap + 4);
    short8 a;
    a[0]=(short)f2bf(av0[0]); a[1]=(short)f2bf(av0[1]); a[2]=(short)f2bf(av0[2]); a[3]=(short)f2bf(av0[3]);
    a[4]=(short)f2bf(av1[0]); a[5]=(short)f2bf(av1[1]); a[6]=(short)f2bf(av1[2]); a[7]=(short)f2bf(av1[3]);
    short8 b = ldsH(sm_h, 16*rh + lo, kf*64 + hi*16);
    acc = MFMA(a, b, acc);
  }
  const size_t outoff = (size_t)head * ((size_t)BATCH * ODIM);
  {
    int grow = row0 + 16*rh + lo;
    #pragma unroll
    for (int j = 0; j < 4; ++j){
      int od = 16*mfo + 4*hi + j;
      float v = acc[j] + bh[od];
      v = (v >= 0.f) ? v : 0.01f*v;
      out[outoff + (size_t)grow*ODIM + od] = v;
    }
  }
}

__global__ __attribute__((amdgpu_flat_work_group_size(NTHR, NTHR)))
void gru_fused(const float* __restrict__ feat, const unsigned short* __restrict__ warr,
               const float* __restrict__ b_ih, const float* __restrict__ b_hh,
               const float* __restrict__ w_pi, const float* __restrict__ b_pi,
               const float* __restrict__ w_vf, const float* __restrict__ b_vf,
               float* __restrict__ out){
  __shared__ __align__(16) unsigned char sm_h[MROWS*512];   // 16 KB
  __shared__ __align__(16) unsigned char sm_x[MROWS*256];   // 8 KB
  __shared__ __align__(16) float biasL[1024];               // 4 KB
  if (blockIdx.x & 1)
    gru_body<6>(feat, warr, b_ih, b_hh, w_pi, b_pi, w_vf, b_vf, out, sm_h, sm_x, biasL);
  else
    gru_body<0>(feat, warr, b_ih, b_hh, w_pi, b_pi, w_vf, b_vf, out, sm_h, sm_x, biasL);
}

extern "C" void kernel_launch(void* const* d_in, const int* in_sizes, int n_in,
                              void* d_out, int out_size, void* d_ws, size_t ws_size,
                              hipStream_t stream){
  const float* feat = (const float*)d_in[0];
  const float* w_ih = (const float*)d_in[1];
  const float* w_hh = (const float*)d_in[2];
  const float* b_ih = (const float*)d_in[3];
  const float* b_hh = (const float*)d_in[4];
  const float* w_pi = (const float*)d_in[5];
  const float* b_pi = (const float*)d_in[6];
  const float* w_vf = (const float*)d_in[7];
  const float* b_vf = (const float*)d_in[8];

  unsigned short* warr = (unsigned short*)d_ws;   // 589824 B

  prep_weights<<<144, 256, 0, stream>>>(w_ih, w_hh, warr);
  gru_fused<<<NBLK, NTHR, 0, stream>>>(feat, warr, b_ih, b_hh,
                                       w_pi, b_pi, w_vf, b_vf, (float*)d_out);
}

// Round 9
// 864.532 us; speedup vs baseline: 1.0590x; 1.0590x over previous
//
#include <hip/hip_runtime.h>

#define BATCH  4096
#define TSTEPS 64
#define FDIM   128
#define HDIM   256
#define ODIM   64
#define MROWS  32
#define NBLK   128    // BATCH / MROWS
#define NTHR   1024   // 16 waves; launch_bounds(,4) -> 1 block/CU, 128 reg/wave

typedef __attribute__((ext_vector_type(8))) short  short8;
typedef __attribute__((ext_vector_type(4))) float  floatx4;

#define MFMA(a,b,c) __builtin_amdgcn_mfma_f32_16x16x32_bf16((a),(b),(c),0,0,0)

__device__ __forceinline__ unsigned short f2bf(float f){
  unsigned u = __builtin_bit_cast(unsigned, f);
  u += 0x7FFFu + ((u >> 16) & 1u);           // RTNE
  return (unsigned short)(u >> 16);
}
__device__ __forceinline__ float sigm(float x){
  return __builtin_amdgcn_rcpf(1.f + __expf(-x));
}
__device__ __forceinline__ float tanh_f(float x){
  return 2.f * __builtin_amdgcn_rcpf(1.f + __expf(-2.f * x)) - 1.f;
}

// ---------------- phase 0: fragment weights into d_ws ----------
// warr[((gf*12 + kf)*64 + lane)*8 + i]; gf 0..47, kf 0..7 = w_hh, 8..11 = w_ih
// element = W[16*gf + (lane&15)][32*kf + 8*(lane>>4) + i]  (A-frag, row=lane&15)
__global__ void prep_weights(const float* __restrict__ w_ih,
                             const float* __restrict__ w_hh,
                             unsigned short* __restrict__ warr){
  int idx = blockIdx.x * 256 + threadIdx.x;
  if (idx >= 48*12*64) return;
  int gf   = idx / 768;
  int rr   = idx - gf*768;
  int kf   = rr >> 6;
  int lane = rr & 63;
  int lo = lane & 15, hi = lane >> 4;
  const float* src = (kf < 8) ? (w_hh + (size_t)(16*gf + lo)*HDIM + 32*kf     + 8*hi)
                              : (w_ih + (size_t)(16*gf + lo)*FDIM + 32*(kf-8) + 8*hi);
  unsigned short* dst = warr + (size_t)idx * 8;
  #pragma unroll
  for (int i = 0; i < 8; ++i) dst[i] = f2bf(src[i]);
}

// ---- LDS swizzle (bank-quad = (col>>4) ^ (row&7); conflict-minimal)
__device__ __forceinline__ short8 ldsH(const unsigned char* sm, int row, int col){
  return *(const short8*)(sm + row*512 + (col ^ ((row & 7) << 4)));
}
__device__ __forceinline__ short8 ldsX(const unsigned char* sm, int row, int col){
  return *(const short8*)(sm + row*256 + (col ^ ((row & 7) << 4)));
}

// load stage S with kf = KFE (3 gate frags)
#define LOADSTG(S, KFE) \
    sa##S##_0 = *(const short8*)(wl + (gfr*12 + (KFE))*512); \
    sa##S##_1 = *(const short8*)(wl + (gfz*12 + (KFE))*512); \
    sa##S##_2 = *(const short8*)(wl + (gfn*12 + (KFE))*512);

// round G consuming stage S; reload stage with kf+4 while MFMAs run
#define RND(G, S) { \
    constexpr int kf_ = ((G) + KOFF) % 12; \
    short8 b0, b1; \
    if constexpr (kf_ < 8){ \
      b0 = ldsH(sm_h, lo,      kf_*64 + hi*16); \
      b1 = ldsH(sm_h, 16 + lo, kf_*64 + hi*16); \
    } else { \
      b0 = ldsX(sm_x, lo,      (kf_-8)*64 + hi*16); \
      b1 = ldsX(sm_x, 16 + lo, (kf_-8)*64 + hi*16); \
    } \
    ar[0] = MFMA(sa##S##_0, b0, ar[0]); ar[1] = MFMA(sa##S##_0, b1, ar[1]); \
    az[0] = MFMA(sa##S##_1, b0, az[0]); az[1] = MFMA(sa##S##_1, b1, az[1]); \
    if constexpr (kf_ < 8){ \
      anh[0] = MFMA(sa##S##_2, b0, anh[0]); anh[1] = MFMA(sa##S##_2, b1, anh[1]); \
    } else { \
      anx[0] = MFMA(sa##S##_2, b0, anx[0]); anx[1] = MFMA(sa##S##_2, b1, anx[1]); \
    } \
    if constexpr ((G) < 8){ \
      constexpr int k2_ = ((G) + 4 + KOFF) % 12; \
      LOADSTG(S, k2_) \
    } \
  }

// ---------------- main fused kernel ----------------
template<int KOFF>
__device__ __forceinline__ void gru_body(
    const float* __restrict__ feat, const unsigned short* __restrict__ warr,
    const float* __restrict__ b_ih, const float* __restrict__ b_hh,
    const float* __restrict__ w_pi, const float* __restrict__ b_pi,
    const float* __restrict__ w_vf, const float* __restrict__ b_vf,
    float* __restrict__ out,
    unsigned char* sm_h, unsigned char* sm_x, float* biasL){

  const int tid  = threadIdx.x;
  const int wv   = tid >> 6;              // 0..15 -> owns h-cols [16wv, 16wv+16)
  const int lane = tid & 63;
  const int lo   = lane & 15, hi = lane >> 4;
  const int row0 = blockIdx.x * MROWS;
  const int cb   = 16*wv + 4*hi;          // gate/h col base for this lane
  const int gfr  = wv, gfz = 16 + wv, gfn = 32 + wv;

  const unsigned short* wl = warr + lane*8;

  // ---- one-time: bias -> LDS
  if      (tid < 512) biasL[tid] = b_ih[tid] + b_hh[tid];   // r,z combined
  else if (tid < 768) biasL[tid] = b_ih[tid];               // xn
  else                biasL[tid] = b_hh[tid - 256];         // hn

  // ---- zero sm_h
  ((int4*)sm_h)[tid] = make_int4(0,0,0,0);
  // ---- stage x[0]
  {
    int r  = tid >> 5;
    int c4 = tid & 31;
    floatx4 v = __builtin_nontemporal_load(
        (const floatx4*)(feat + (size_t)(row0 + r)*(TSTEPS*FDIM)) + c4);
    uint2 pk;
    pk.x = (unsigned)f2bf(v[0]) | ((unsigned)f2bf(v[1]) << 16);
    pk.y = (unsigned)f2bf(v[2]) | ((unsigned)f2bf(v[3]) << 16);
    *(uint2*)(sm_x + r*256 + ((c4*8) ^ ((r & 7) << 4))) = pk;
  }

  float hold[2][4];
  #pragma unroll
  for (int m = 0; m < 2; ++m)
    #pragma unroll
    for (int j = 0; j < 4; ++j) hold[m][j] = 0.f;

  __syncthreads();

  const int xr  = tid >> 5;
  const int xc4 = tid & 31;

  #pragma unroll 1
  for (int t = 0; t < TSTEPS; ++t){
    // ---- depth-4 A prefetch: fill all 4 stages first (12 loads in flight)
    short8 sa0_0, sa0_1, sa0_2, sa1_0, sa1_1, sa1_2;
    short8 sa2_0, sa2_1, sa2_2, sa3_0, sa3_1, sa3_2;
    {
      constexpr int k0 = (0 + KOFF) % 12;
      constexpr int k1 = (1 + KOFF) % 12;
      constexpr int k2 = (2 + KOFF) % 12;
      constexpr int k3 = (3 + KOFF) % 12;
      LOADSTG(0, k0)
      LOADSTG(1, k1)
      LOADSTG(2, k2)
      LOADSTG(3, k3)
    }

    // ---- prefetch x[t+1]
    int tn = (t < TSTEPS-1) ? (t+1) : (TSTEPS-1);
    floatx4 xf = __builtin_nontemporal_load(
        (const floatx4*)(feat + (size_t)(row0 + xr)*(TSTEPS*FDIM) + (size_t)tn*FDIM) + xc4);

    // ---- acc init from LDS bias
    floatx4 ar[2], az[2], anh[2], anx[2];
    {
      floatx4 vr = *(const floatx4*)(biasL + cb);
      floatx4 vz = *(const floatx4*)(biasL + 256 + cb);
      floatx4 vx = *(const floatx4*)(biasL + 512 + cb);
      floatx4 vh = *(const floatx4*)(biasL + 768 + cb);
      #pragma unroll
      for (int m = 0; m < 2; ++m){ ar[m] = vr; az[m] = vz; anh[m] = vh; anx[m] = vx; }
    }

    // ---- 12 rounds, 4-stage rotation
    RND(0,0)  RND(1,1)  RND(2,2)  RND(3,3)
    RND(4,0)  RND(5,1)  RND(6,2)  RND(7,3)
    RND(8,0)  RND(9,1)  RND(10,2) RND(11,3)

    __syncthreads();   // all sm_h / sm_x reads of this step done

    // ---- write x[t+1]
    if (t < TSTEPS-1){
      uint2 pk;
      pk.x = (unsigned)f2bf(xf[0]) | ((unsigned)f2bf(xf[1]) << 16);
      pk.y = (unsigned)f2bf(xf[2]) | ((unsigned)f2bf(xf[3]) << 16);
      *(uint2*)(sm_x + xr*256 + ((xc4*8) ^ ((xr & 7) << 4))) = pk;
    }

    // ---- lane-local gate math; write h_new (bf16, swizzled, 8B packed)
    #pragma unroll
    for (int m = 0; m < 2; ++m){
      int row = 16*m + lo;
      unsigned q[4];
      #pragma unroll
      for (int j = 0; j < 4; ++j){
        float r  = sigm(ar[m][j]);
        float z  = sigm(az[m][j]);
        float n  = tanh_f(anx[m][j] + r*anh[m][j]);
        float hv = (1.f - z)*n + z*hold[m][j];
        hold[m][j] = hv;
        q[j] = f2bf(hv);
      }
      uint2 pk; pk.x = q[0] | (q[1] << 16); pk.y = q[2] | (q[3] << 16);
      *(uint2*)(sm_h + row*512 + ((cb*2) ^ ((row & 7) << 4))) = pk;
    }
    __syncthreads();   // h[t+1], x[t+1] visible
  }

  // ---- epilogue: leaky(h_last) -> sm_h (bf16)
  #pragma unroll
  for (int m = 0; m < 2; ++m){
    int row = 16*m + lo;
    unsigned q[4];
    #pragma unroll
    for (int j = 0; j < 4; ++j){
      float v = hold[m][j];
      v = (v >= 0.f) ? v : 0.01f*v;
      q[j] = f2bf(v);
    }
    uint2 pk; pk.x = q[0] | (q[1] << 16); pk.y = q[2] | (q[3] << 16);
    *(uint2*)(sm_h + row*512 + ((cb*2) ^ ((row & 7) << 4))) = pk;
  }
  __syncthreads();

  // ---- heads: 16 waves = 2 heads x 4 out-frags x 2 row-frags
  const int head = wv >> 3;
  const int mfo  = (wv >> 1) & 3;
  const int rh   = wv & 1;
  const float* wh = head ? w_vf : w_pi;
  const float* bh = head ? b_vf : b_pi;
  floatx4 acc = {0.f,0.f,0.f,0.f};
  #pragma unroll
  for (int kf = 0; kf < 8; ++kf){
    const float* ap = wh + (size_t)(16*mfo + lo)*HDIM + 32*kf + 8*hi;
    floatx4 av0 = *(const floatx4*)ap;
    floatx4 av1 = *(const floatx4*)(ap + 4);
    short8 a;
    a[0]=(short)f2bf(av0[0]); a[1]=(short)f2bf(av0[1]); a[2]=(short)f2bf(av0[2]); a[3]=(short)f2bf(av0[3]);
    a[4]=(short)f2bf(av1[0]); a[5]=(short)f2bf(av1[1]); a[6]=(short)f2bf(av1[2]); a[7]=(short)f2bf(av1[3]);
    short8 b = ldsH(sm_h, 16*rh + lo, kf*64 + hi*16);
    acc = MFMA(a, b, acc);
  }
  const size_t outoff = (size_t)head * ((size_t)BATCH * ODIM);
  {
    int grow = row0 + 16*rh + lo;
    #pragma unroll
    for (int j = 0; j < 4; ++j){
      int od = 16*mfo + 4*hi + j;
      float v = acc[j] + bh[od];
      v = (v >= 0.f) ? v : 0.01f*v;
      out[outoff + (size_t)grow*ODIM + od] = v;
    }
  }
}

__global__ __launch_bounds__(NTHR, 4)
void gru_fused(const float* __restrict__ feat, const unsigned short* __restrict__ warr,
               const float* __restrict__ b_ih, const float* __restrict__ b_hh,
               const float* __restrict__ w_pi, const float* __restrict__ b_pi,
               const float* __restrict__ w_vf, const float* __restrict__ b_vf,
               float* __restrict__ out){
  __shared__ __align__(16) unsigned char sm_h[MROWS*512];   // 16 KB
  __shared__ __align__(16) unsigned char sm_x[MROWS*256];   // 8 KB
  __shared__ __align__(16) float biasL[1024];               // 4 KB
  if (blockIdx.x & 1)
    gru_body<6>(feat, warr, b_ih, b_hh, w_pi, b_pi, w_vf, b_vf, out, sm_h, sm_x, biasL);
  else
    gru_body<0>(feat, warr, b_ih, b_hh, w_pi, b_pi, w_vf, b_vf, out, sm_h, sm_x, biasL);
}

extern "C" void kernel_launch(void* const* d_in, const int* in_sizes, int n_in,
                              void* d_out, int out_size, void* d_ws, size_t ws_size,
                              hipStream_t stream){
  const float* feat = (const float*)d_in[0];
  const float* w_ih = (const float*)d_in[1];
  const float* w_hh = (const float*)d_in[2];
  const float* b_ih = (const float*)d_in[3];
  const float* b_hh = (const float*)d_in[4];
  const float* w_pi = (const float*)d_in[5];
  const float* b_pi = (const float*)d_in[6];
  const float* w_vf = (const float*)d_in[7];
  const float* b_vf = (const float*)d_in[8];

  unsigned short* warr = (unsigned short*)d_ws;   // 589824 B

  prep_weights<<<144, 256, 0, stream>>>(w_ih, w_hh, warr);
  gru_fused<<<NBLK, NTHR, 0, stream>>>(feat, warr, b_ih, b_hh,
                                       w_pi, b_pi, w_vf, b_vf, (float*)d_out);
}